// Round 14
// baseline (147.855 us; speedup 1.0000x reference)
//
#include <hip/hip_runtime.h>
#include <math.h>

#define C_CLASSES 100000
#define FEAT      512
#define BATCH_N   32768
#define EPS_N     1e-12f
#define NBLKA     2048
#define MSLOTS    32
#define LSLOTS    64
#define FIX_SCALE 4294967296.0   // 2^32

typedef float vf4 __attribute__((ext_vector_type(4)));

// ---------------- Kernel N: PURE-READ normalize pass ----------------
// Streams centers once (read-only -> should run at the ~6.3 TB/s read ceiling),
// computes rnorms + fixed-point mean partials. Also warms L3 with centers for
// row_loss's gather and copy_shift's reads.
__global__ void __launch_bounds__(256) norm_pass(
    const float* __restrict__ centers,
    unsigned long long* __restrict__ mslots,       // [MSLOTS*FEAT]
    float* __restrict__ rnorms)                    // [C_CLASSES]
{
    const int t   = threadIdx.x;
    const int wid = t >> 6;
    const int ln  = t & 63;
    const int nb  = gridDim.x;

    float acc[8] = {0.f,0.f,0.f,0.f,0.f,0.f,0.f,0.f};

    for (int row = blockIdx.x * 4 + wid; row < C_CLASSES; row += nb * 4) {
        const float4* rp4 = reinterpret_cast<const float4*>(centers + (size_t)row * FEAT);
        const float4 v0 = rp4[ln];
        const float4 v1 = rp4[ln + 64];

        float ss = v0.x*v0.x + v0.y*v0.y + v0.z*v0.z + v0.w*v0.w
                 + v1.x*v1.x + v1.y*v1.y + v1.z*v1.z + v1.w*v1.w;
        #pragma unroll
        for (int o = 32; o > 0; o >>= 1) ss += __shfl_xor(ss, o, 64);

        const float rn = 1.f / fmaxf(sqrtf(ss), EPS_N);
        if (ln == 0) rnorms[row] = rn;

        acc[0] += v0.x * rn; acc[1] += v0.y * rn; acc[2] += v0.z * rn; acc[3] += v0.w * rn;
        acc[4] += v1.x * rn; acc[5] += v1.y * rn; acc[6] += v1.z * rn; acc[7] += v1.w * rn;
    }

    __shared__ float accsh[4][FEAT];
    accsh[wid][4*ln + 0] = acc[0]; accsh[wid][4*ln + 1] = acc[1];
    accsh[wid][4*ln + 2] = acc[2]; accsh[wid][4*ln + 3] = acc[3];
    accsh[wid][256 + 4*ln + 0] = acc[4]; accsh[wid][256 + 4*ln + 1] = acc[5];
    accsh[wid][256 + 4*ln + 2] = acc[6]; accsh[wid][256 + 4*ln + 3] = acc[7];
    __syncthreads();

    const int slot = (blockIdx.x & (MSLOTS - 1)) * FEAT;
    for (int j = t; j < FEAT; j += 256) {
        const float v = accsh[0][j] + accsh[1][j] + accsh[2][j] + accsh[3][j];
        const long long q = llrint((double)v * FIX_SCALE);
        atomicAdd(&mslots[slot + j], (unsigned long long)q);
    }
}

// ---------------- Kernel B: mslots -> mean[512] ----------------
__global__ void __launch_bounds__(512) mean_fin(
    const unsigned long long* __restrict__ mslots,
    float* __restrict__ mean)
{
    const int j = threadIdx.x;
    long long s = 0;
    #pragma unroll
    for (int p = 0; p < MSLOTS; ++p)
        s += (long long)mslots[(size_t)p * FEAT + j];
    mean[j] = (float)((double)s * (1.0 / FIX_SCALE) / (double)C_CLASSES);
}

// ---------------- Kernel C: per-x-row loss terms (one wave per row) ----------------
__global__ void __launch_bounds__(256) row_loss(
    const float* __restrict__ x,
    const int*   __restrict__ labels,
    const float* __restrict__ centers,
    const float* __restrict__ mean,
    const float* __restrict__ rnorms,
    unsigned long long* __restrict__ lslots)       // [LSLOTS*2]
{
    const int wid = threadIdx.x >> 6;
    const int ln  = threadIdx.x & 63;
    const int row = blockIdx.x * 4 + wid;

    const float4* __restrict__ xr = reinterpret_cast<const float4*>(x + (size_t)row * FEAT);
    const float4* __restrict__ mr = reinterpret_cast<const float4*>(mean);
    const int lab = labels[row];
    const float4* __restrict__ cr = reinterpret_cast<const float4*>(centers + (size_t)lab * FEAT);
    const float rnc = rnorms[lab];

    const float4 xv0 = xr[ln], xv1 = xr[ln + 64];
    const float4 mv0 = mr[ln], mv1 = mr[ln + 64];
    const float4 cv0 = cr[ln], cv1 = cr[ln + 64];

    float ssx = xv0.x*xv0.x + xv0.y*xv0.y + xv0.z*xv0.z + xv0.w*xv0.w
              + xv1.x*xv1.x + xv1.y*xv1.y + xv1.z*xv1.z + xv1.w*xv1.w;
    float dxm = xv0.x*mv0.x + xv0.y*mv0.y + xv0.z*mv0.z + xv0.w*mv0.w
              + xv1.x*mv1.x + xv1.y*mv1.y + xv1.z*mv1.z + xv1.w*mv1.w;
    float dxc = xv0.x*cv0.x + xv0.y*cv0.y + xv0.z*cv0.z + xv0.w*cv0.w
              + xv1.x*cv1.x + xv1.y*cv1.y + xv1.z*cv1.z + xv1.w*cv1.w;

    #pragma unroll
    for (int o = 32; o > 0; o >>= 1) {
        ssx += __shfl_xor(ssx, o, 64);
        dxm += __shfl_xor(dxm, o, 64);
        dxc += __shfl_xor(dxc, o, 64);
    }

    __shared__ float t1s[4], t2s[4];
    if (ln == 0) {
        const float rnx = 1.f / fmaxf(sqrtf(ssx), EPS_N);
        const float s_all = dxm * rnx;
        const float s_lab = dxc * rnx * rnc;
        const float e_all = expf(s_all);
        const float kC    = (float)((double)(C_CLASSES + 1) / (double)C_CLASSES);
        t1s[wid] = (e_all - expf(s_lab * kC));                        // / ALPHA1 (=1)
        t2s[wid] = -fabsf((e_all - expf(s_lab) + 0.2f) * (1.f / 50.f));
    }
    __syncthreads();
    if (threadIdx.x == 0) {
        const double b1 = (double)t1s[0] + t1s[1] + t1s[2] + t1s[3];
        const double b2 = (double)t2s[0] + t2s[1] + t2s[2] + t2s[3];
        const int slot = (blockIdx.x & (LSLOTS - 1)) * 2;
        atomicAdd(&lslots[slot + 0], (unsigned long long)llrint(b1 * FIX_SCALE));
        atomicAdd(&lslots[slot + 1], (unsigned long long)llrint(b2 * FIX_SCALE));
    }
}

// ---------------- Kernel CP: PURE-WRITE shifted copy (runs last) ----------------
// Flat float4 copy with the R8 shift: out4[i] = {centers[4i-1], c[4i], c[4i+1],
// c[4i+2]} -> every store is 16B-aligned and the span is dense. NT stores keep
// the write-once stream out of L2/L3 (centers stays resident for next replay).
// Reads mostly hit the L3 warmed by norm_pass/row_loss.
__global__ void __launch_bounds__(256) copy_shift(
    const float* __restrict__ centers,
    float* __restrict__ out)           // d_out (aligned base)
{
    const size_t NV4 = (size_t)C_CLASSES * FEAT / 4;   // 12,800,000 float4s
    const int ln = threadIdx.x & 63;
    const size_t stride = (size_t)gridDim.x * 256;

    for (size_t i = (size_t)blockIdx.x * 256 + threadIdx.x; i < NV4; i += stride) {
        const float4 v = reinterpret_cast<const float4*>(centers)[i];
        const float up = __shfl_up(v.w, 1, 64);        // full exec (R7 lesson)

        float lead = up;
        if (ln == 0 && i > 0) lead = centers[4 * i - 1];   // divergent LOAD: fine

        vf4 s;
        s.x = (ln == 0) ? lead : up;
        s.y = v.x; s.z = v.y; s.w = v.z;

        if (i == 0 && ln == 0) {
            out[1] = v.x; out[2] = v.y; out[3] = v.z;  // out[0] = loss slot
        } else {
            __builtin_nontemporal_store(s, &reinterpret_cast<vf4*>(out)[i]);
        }
    }
}

// ---------------- Kernel D: finalize loss + copy tail dword ----------------
__global__ void loss_fin(const unsigned long long* __restrict__ lslots,
                         const int* __restrict__ epoch,
                         const float* __restrict__ centers,
                         float* __restrict__ out)
{
    if (threadIdx.x == 0) {
        long long q1 = 0, q2 = 0;
        for (int p = 0; p < LSLOTS; ++p) {
            q1 += (long long)lslots[(size_t)p * 2 + 0];
            q2 += (long long)lslots[(size_t)p * 2 + 1];
        }
        const float v  = fminf((float)(*epoch) * (1.f / 14.f), 1.f);
        const float l1 = (float)((double)q1 * (1.0 / FIX_SCALE) / (double)BATCH_N);
        const float l2 = (float)((double)q2 * (1.0 / FIX_SCALE) / (double)BATCH_N);
        out[0] = (1.f - v) * l1 + v * l2;
    }
    if (threadIdx.x == 1) {
        const size_t g = (size_t)C_CLASSES * FEAT;     // last copy dword
        out[g] = centers[g - 1];
    }
}

extern "C" void kernel_launch(void* const* d_in, const int* in_sizes, int n_in,
                              void* d_out, int out_size, void* d_ws, size_t ws_size,
                              hipStream_t stream)
{
    const float* x       = (const float*)d_in[0];
    const int*   labels  = (const int*)d_in[1];
    // d_in[2] = ori_labels (unused by reference)
    const int*   epoch   = (const int*)d_in[3];
    const float* centers = (const float*)d_in[4];
    float* out = (float*)d_out;

    float* ws = (float*)d_ws;
    float* mean = ws;                                              // 512 f
    unsigned long long* mslots = (unsigned long long*)(ws + 512);  // 32*512 ll
    unsigned long long* lslots = mslots + (size_t)MSLOTS * FEAT;   // 64*2 ll
    float* rnorms = ws + 512 + 2 * (MSLOTS * FEAT + LSLOTS * 2);   // C_CLASSES f

    (void)hipMemsetAsync(mslots, 0,
                   (size_t)(MSLOTS * FEAT + LSLOTS * 2) * sizeof(unsigned long long),
                   stream);

    norm_pass<<<NBLKA, 256, 0, stream>>>(centers, mslots, rnorms);
    mean_fin<<<1, 512, 0, stream>>>(mslots, mean);
    row_loss<<<BATCH_N / 4, 256, 0, stream>>>(x, labels, centers, mean, rnorms, lslots);
    copy_shift<<<NBLKA, 256, 0, stream>>>(centers, out);
    loss_fin<<<1, 64, 0, stream>>>(lslots, epoch, centers, out);
}

// Round 15
// 119.114 us; speedup vs baseline: 1.2413x; 1.2413x over previous
//
#include <hip/hip_runtime.h>
#include <math.h>

#define C_CLASSES 100000
#define FEAT      512
#define BATCH_N   32768
#define EPS_N     1e-12f
#define NBLKA     2048
#define MSLOTS    32
#define LSLOTS    64
#define FIX_SCALE 4294967296.0   // 2^32

typedef float vf4 __attribute__((ext_vector_type(4)));   // native vector: OK for nontemporal builtin

// ---------------- Kernel A: wave-per-row normalize-accumulate + ALIGNED NT copy ----------------
// Best-known configuration (R13, 120.7 us): single mixed-stream pass over
// centers; shifted aligned float4 copy (R8 trick) with NONTEMPORAL stores;
// fixed-point atomic partial means (deterministic integer adds); rnorms cached
// for row_loss.
__global__ void __launch_bounds__(256) centers_pass(
    const float* __restrict__ centers,
    float* __restrict__ out,                       // d_out (aligned base)
    unsigned long long* __restrict__ mslots,       // [MSLOTS*FEAT] fixed-point
    float* __restrict__ rnorms)                    // [C_CLASSES]
{
    const int t   = threadIdx.x;
    const int wid = t >> 6;
    const int ln  = t & 63;
    const int nb  = gridDim.x;

    float acc[8] = {0.f,0.f,0.f,0.f,0.f,0.f,0.f,0.f};

    for (int row = blockIdx.x * 4 + wid; row < C_CLASSES; row += nb * 4) {
        const size_t rbase = (size_t)row * FEAT;
        const float4* rp4 = reinterpret_cast<const float4*>(centers + rbase);

        const float4 v0 = rp4[ln];
        const float4 v1 = rp4[ln + 64];
        const float prev_row = (row > 0) ? centers[rbase - 1] : 0.f;

        // ---- shifted aligned copy FIRST (depends only on loads) ----
        const float w0up = __shfl_up(v0.w, 1, 64);      // full exec mask (R7 lesson)
        const float w1up = __shfl_up(v1.w, 1, 64);
        const float w063 = __shfl(v0.w, 63, 64);

        vf4* op4 = reinterpret_cast<vf4*>(out + rbase);
        vf4 s0, s1;
        s0.x = (ln == 0) ? prev_row : w0up; s0.y = v0.x; s0.z = v0.y; s0.w = v0.z;
        s1.x = (ln == 0) ? w063     : w1up; s1.y = v1.x; s1.z = v1.y; s1.w = v1.z;
        if (row == 0 && ln == 0) {
            out[1] = s0.y; out[2] = s0.z; out[3] = s0.w;   // out[0] = loss slot
        } else {
            __builtin_nontemporal_store(s0, &op4[ln]);
        }
        __builtin_nontemporal_store(s1, &op4[ln + 64]);

        // ---- then the reduction ----
        float ss = v0.x*v0.x + v0.y*v0.y + v0.z*v0.z + v0.w*v0.w
                 + v1.x*v1.x + v1.y*v1.y + v1.z*v1.z + v1.w*v1.w;
        #pragma unroll
        for (int o = 32; o > 0; o >>= 1) ss += __shfl_xor(ss, o, 64);

        const float rn = 1.f / fmaxf(sqrtf(ss), EPS_N);
        if (ln == 0) rnorms[row] = rn;

        acc[0] += v0.x * rn; acc[1] += v0.y * rn; acc[2] += v0.z * rn; acc[3] += v0.w * rn;
        acc[4] += v1.x * rn; acc[5] += v1.y * rn; acc[6] += v1.z * rn; acc[7] += v1.w * rn;
    }

    __shared__ float accsh[4][FEAT];
    accsh[wid][4*ln + 0] = acc[0]; accsh[wid][4*ln + 1] = acc[1];
    accsh[wid][4*ln + 2] = acc[2]; accsh[wid][4*ln + 3] = acc[3];
    accsh[wid][256 + 4*ln + 0] = acc[4]; accsh[wid][256 + 4*ln + 1] = acc[5];
    accsh[wid][256 + 4*ln + 2] = acc[6]; accsh[wid][256 + 4*ln + 3] = acc[7];
    __syncthreads();

    const int slot = (blockIdx.x & (MSLOTS - 1)) * FEAT;
    for (int j = t; j < FEAT; j += 256) {
        const float v = accsh[0][j] + accsh[1][j] + accsh[2][j] + accsh[3][j];
        const long long q = llrint((double)v * FIX_SCALE);
        atomicAdd(&mslots[slot + j], (unsigned long long)q);
    }
}

// ---------------- Kernel B: mslots -> mean[512] ----------------
__global__ void __launch_bounds__(512) mean_fin(
    const unsigned long long* __restrict__ mslots,
    float* __restrict__ mean)
{
    const int j = threadIdx.x;
    long long s = 0;
    #pragma unroll
    for (int p = 0; p < MSLOTS; ++p)
        s += (long long)mslots[(size_t)p * FEAT + j];
    mean[j] = (float)((double)s * (1.0 / FIX_SCALE) / (double)C_CLASSES);
}

// ---------------- Kernel C: per-x-row loss terms (one wave per row) ----------------
__global__ void __launch_bounds__(256) row_loss(
    const float* __restrict__ x,
    const int*   __restrict__ labels,
    const float* __restrict__ centers,
    const float* __restrict__ mean,
    const float* __restrict__ rnorms,
    unsigned long long* __restrict__ lslots)       // [LSLOTS*2] fixed-point
{
    const int wid = threadIdx.x >> 6;
    const int ln  = threadIdx.x & 63;
    const int row = blockIdx.x * 4 + wid;

    const float4* __restrict__ xr = reinterpret_cast<const float4*>(x + (size_t)row * FEAT);
    const float4* __restrict__ mr = reinterpret_cast<const float4*>(mean);
    const int lab = labels[row];
    const float4* __restrict__ cr = reinterpret_cast<const float4*>(centers + (size_t)lab * FEAT);
    const float rnc = rnorms[lab];

    const float4 xv0 = xr[ln], xv1 = xr[ln + 64];
    const float4 mv0 = mr[ln], mv1 = mr[ln + 64];
    const float4 cv0 = cr[ln], cv1 = cr[ln + 64];

    float ssx = xv0.x*xv0.x + xv0.y*xv0.y + xv0.z*xv0.z + xv0.w*xv0.w
              + xv1.x*xv1.x + xv1.y*xv1.y + xv1.z*xv1.z + xv1.w*xv1.w;
    float dxm = xv0.x*mv0.x + xv0.y*mv0.y + xv0.z*mv0.z + xv0.w*mv0.w
              + xv1.x*mv1.x + xv1.y*mv1.y + xv1.z*mv1.z + xv1.w*mv1.w;
    float dxc = xv0.x*cv0.x + xv0.y*cv0.y + xv0.z*cv0.z + xv0.w*cv0.w
              + xv1.x*cv1.x + xv1.y*cv1.y + xv1.z*cv1.z + xv1.w*cv1.w;

    #pragma unroll
    for (int o = 32; o > 0; o >>= 1) {
        ssx += __shfl_xor(ssx, o, 64);
        dxm += __shfl_xor(dxm, o, 64);
        dxc += __shfl_xor(dxc, o, 64);
    }

    __shared__ float t1s[4], t2s[4];
    if (ln == 0) {
        const float rnx = 1.f / fmaxf(sqrtf(ssx), EPS_N);
        const float s_all = dxm * rnx;
        const float s_lab = dxc * rnx * rnc;
        const float e_all = expf(s_all);
        const float kC    = (float)((double)(C_CLASSES + 1) / (double)C_CLASSES);
        t1s[wid] = (e_all - expf(s_lab * kC));                        // / ALPHA1 (=1)
        t2s[wid] = -fabsf((e_all - expf(s_lab) + 0.2f) * (1.f / 50.f));
    }
    __syncthreads();
    if (threadIdx.x == 0) {
        const double b1 = (double)t1s[0] + t1s[1] + t1s[2] + t1s[3];
        const double b2 = (double)t2s[0] + t2s[1] + t2s[2] + t2s[3];
        const int slot = (blockIdx.x & (LSLOTS - 1)) * 2;
        atomicAdd(&lslots[slot + 0], (unsigned long long)llrint(b1 * FIX_SCALE));
        atomicAdd(&lslots[slot + 1], (unsigned long long)llrint(b2 * FIX_SCALE));
    }
}

// ---------------- Kernel D: finalize loss + copy tail dword ----------------
__global__ void loss_fin(const unsigned long long* __restrict__ lslots,
                         const int* __restrict__ epoch,
                         const float* __restrict__ centers,
                         float* __restrict__ out)
{
    if (threadIdx.x == 0) {
        long long q1 = 0, q2 = 0;
        for (int p = 0; p < LSLOTS; ++p) {
            q1 += (long long)lslots[(size_t)p * 2 + 0];
            q2 += (long long)lslots[(size_t)p * 2 + 1];
        }
        const float v  = fminf((float)(*epoch) * (1.f / 14.f), 1.f);
        const float l1 = (float)((double)q1 * (1.0 / FIX_SCALE) / (double)BATCH_N);
        const float l2 = (float)((double)q2 * (1.0 / FIX_SCALE) / (double)BATCH_N);
        out[0] = (1.f - v) * l1 + v * l2;
    }
    if (threadIdx.x == 1) {
        const size_t g = (size_t)C_CLASSES * FEAT;   // last copy dword
        out[g] = centers[g - 1];
    }
}

extern "C" void kernel_launch(void* const* d_in, const int* in_sizes, int n_in,
                              void* d_out, int out_size, void* d_ws, size_t ws_size,
                              hipStream_t stream)
{
    const float* x       = (const float*)d_in[0];
    const int*   labels  = (const int*)d_in[1];
    // d_in[2] = ori_labels (unused by reference)
    const int*   epoch   = (const int*)d_in[3];
    const float* centers = (const float*)d_in[4];
    float* out = (float*)d_out;

    float* ws = (float*)d_ws;
    float* mean = ws;                                              // 512 f
    unsigned long long* mslots = (unsigned long long*)(ws + 512);  // 32*512 ll (8B-aligned)
    unsigned long long* lslots = mslots + (size_t)MSLOTS * FEAT;   // 64*2 ll
    float* rnorms = ws + 512 + 2 * (MSLOTS * FEAT + LSLOTS * 2);   // C_CLASSES floats

    // zero the atomic slots (capture-safe async memset)
    (void)hipMemsetAsync(mslots, 0,
                   (size_t)(MSLOTS * FEAT + LSLOTS * 2) * sizeof(unsigned long long),
                   stream);

    centers_pass<<<NBLKA, 256, 0, stream>>>(centers, out, mslots, rnorms);
    mean_fin<<<1, 512, 0, stream>>>(mslots, mean);
    row_loss<<<BATCH_N / 4, 256, 0, stream>>>(x, labels, centers, mean, rnorms, lslots);
    loss_fin<<<1, 64, 0, stream>>>(lslots, epoch, centers, out);
}